// Round 1
// baseline (149.897 us; speedup 1.0000x reference)
//
#include <hip/hip_runtime.h>
#include <math.h>

// Problem constants
#define HH 256
#define SS 32768
#define BB 8
#define NEGV (-10000000000.0f)

// Output layout (floats): result(2048) | h_new(2048) | evidence(8) | attn(262144) | new_mask(262144)
#define OUT_RESULT 0
#define OUT_HNEW   2048
#define OUT_EV     4096
#define OUT_ATT    4104
#define OUT_MASK   266248

// Workspace layout (floats)
#define WS_HNEW 0
#define WS_Q1   2048
#define WS_C1   4096
#define WS_PART 4112
#define PART_STRIDE 264   // ctx[256] + m,l,bestv,bestidx (+pad)
#define CHUNKS_PER_B 128  // 128 chunks * 256 s = 32768

// ---------------- Kernel A: GRU step + q1/c1 precompute ----------------
__global__ __launch_bounds__(256) void gru_prep(
    const float* __restrict__ last_hidden, const float* __restrict__ dec_in,
    const float* __restrict__ W1, const float* __restrict__ b1,
    const float* __restrict__ W_ih, const float* __restrict__ W_hh,
    const float* __restrict__ b_ih, const float* __restrict__ b_hh,
    float* __restrict__ ws, float* __restrict__ out)
{
    const int b = blockIdx.x, t = threadIdx.x;
    __shared__ __align__(16) float xs[HH], hs[HH], hn[HH];
    __shared__ float red[256];
    xs[t] = dec_in[b * HH + t];          // decoder_inputs (B,1,H)
    hs[t] = last_hidden[b * HH + t];     // last_hidden (1,B,H)
    __syncthreads();

    const float4* Wi4 = (const float4*)W_ih;
    const float4* Wh4 = (const float4*)W_hh;
    const float4* xs4 = (const float4*)xs;
    const float4* hs4 = (const float4*)hs;

    float gi0 = b_ih[t], gi1 = b_ih[t + HH], gi2 = b_ih[t + 2 * HH];
    float gh0 = b_hh[t], gh1 = b_hh[t + HH], gh2 = b_hh[t + 2 * HH];
    #pragma unroll 4
    for (int k4 = 0; k4 < HH / 4; ++k4) {
        float4 xv = xs4[k4], hv = hs4[k4];
        float4 a0 = Wi4[(size_t)(t)          * (HH/4) + k4];
        float4 a1 = Wi4[(size_t)(t + HH)     * (HH/4) + k4];
        float4 a2 = Wi4[(size_t)(t + 2*HH)   * (HH/4) + k4];
        float4 c0 = Wh4[(size_t)(t)          * (HH/4) + k4];
        float4 c1v= Wh4[(size_t)(t + HH)     * (HH/4) + k4];
        float4 c2 = Wh4[(size_t)(t + 2*HH)   * (HH/4) + k4];
        gi0 += xv.x*a0.x + xv.y*a0.y + xv.z*a0.z + xv.w*a0.w;
        gi1 += xv.x*a1.x + xv.y*a1.y + xv.z*a1.z + xv.w*a1.w;
        gi2 += xv.x*a2.x + xv.y*a2.y + xv.z*a2.z + xv.w*a2.w;
        gh0 += hv.x*c0.x + hv.y*c0.y + hv.z*c0.z + hv.w*c0.w;
        gh1 += hv.x*c1v.x+ hv.y*c1v.y+ hv.z*c1v.z+ hv.w*c1v.w;
        gh2 += hv.x*c2.x + hv.y*c2.y + hv.z*c2.z + hv.w*c2.w;
    }
    float r = 1.0f / (1.0f + expf(-(gi0 + gh0)));
    float z = 1.0f / (1.0f + expf(-(gi1 + gh1)));
    float n = tanhf(gi2 + r * gh2);
    float hnew = (1.0f - z) * n + z * hs[t];

    ws[WS_HNEW + b * HH + t] = hnew;
    out[OUT_HNEW + b * HH + t] = hnew;
    hn[t] = hnew;
    red[t] = hnew * b1[t];
    __syncthreads();

    // q1[k] = sum_h hn[h] * W1[h,k]  (coalesced over t=k)
    float acc = 0.0f;
    #pragma unroll 4
    for (int h = 0; h < HH; ++h) acc += hn[h] * W1[(size_t)h * HH + t];
    ws[WS_Q1 + b * HH + t] = acc;

    // c1 = hn . b1
    for (int s = 128; s > 0; s >>= 1) {
        if (t < s) red[t] += red[t + s];
        __syncthreads();
    }
    if (t == 0) ws[WS_C1 + b] = red[0];
}

// ---------------- Kernel B: streaming scores + online softmax context ----------------
__global__ __launch_bounds__(256) void attn_main(
    const float* __restrict__ eo, const float* __restrict__ mask,
    const float* __restrict__ gum, float* __restrict__ ws,
    float* __restrict__ out)
{
    const int blk = blockIdx.x;
    const int b = blk >> 7;            // CHUNKS_PER_B = 128
    const int chunk = blk & 127;
    const int t = threadIdx.x;
    const int w = t >> 6, lane = t & 63;
    const int sbase = chunk * 256;
    const int swave = sbase + w * 64;

    // mask pass-through copy (overwritten at evidence by finalize)
    {
        int s = sbase + t;
        out[OUT_MASK + (size_t)b * SS + s] = mask[(size_t)b * SS + s];
    }

    const float4* q4 = (const float4*)(ws + WS_Q1 + b * HH);
    const float4 q = q4[lane];
    const float c1 = ws[WS_C1 + b];

    const int sl = swave + lane;
    const float mk = mask[(size_t)b * SS + sl];
    const float uu = gum[(size_t)b * SS + sl];
    const float gl = -logf(-logf(uu));

    const float4* base = (const float4*)(eo + ((size_t)b * SS + swave) * HH);

    float m = -INFINITY, l = 0.0f;
    float bv = -INFINITY; int bi = 0;
    float4 ctx = {0.f, 0.f, 0.f, 0.f};
    float my_t = 0.0f;

    float4 v = base[lane];  // prefetch it=0
    #pragma unroll 4
    for (int it = 0; it < 64; ++it) {
        float4 vn = {0.f, 0.f, 0.f, 0.f};
        if (it < 63) vn = base[(size_t)(it + 1) * (HH/4) + lane];

        float p = v.x*q.x + v.y*q.y + v.z*q.z + v.w*q.w;
        #pragma unroll
        for (int off = 32; off > 0; off >>= 1) p += __shfl_xor(p, off);

        float tt = p + c1 + __shfl(mk, it);   // attn_outputs value (no gumbel)
        if (it == lane) my_t = tt;
        float tg = tt + __shfl(gl, it);

        if (tg > bv) { bv = tg; bi = swave + it; }   // first-max tie-break (ascending)

        if (tg > m) {                                 // wave-uniform branch
            float sc = __expf(m - tg);
            l *= sc; ctx.x *= sc; ctx.y *= sc; ctx.z *= sc; ctx.w *= sc;
            m = tg;
        }
        float wgt = __expf(tg - m);
        l += wgt;
        ctx.x += wgt * v.x; ctx.y += wgt * v.y; ctx.z += wgt * v.z; ctx.w += wgt * v.w;
        v = vn;
    }

    out[OUT_ATT + (size_t)b * SS + swave + lane] = my_t;

    // combine 4 waves -> 1 block partial
    __shared__ float pm[4], pl[4], pbv[4];
    __shared__ int pbi[4];
    __shared__ __align__(16) float pctx[4][HH];
    ((float4*)pctx[w])[lane] = ctx;
    if (lane == 0) { pm[w] = m; pl[w] = l; pbv[w] = bv; pbi[w] = bi; }
    __syncthreads();

    float M = fmaxf(fmaxf(pm[0], pm[1]), fmaxf(pm[2], pm[3]));
    float e0 = __expf(pm[0] - M), e1 = __expf(pm[1] - M);
    float e2 = __expf(pm[2] - M), e3 = __expf(pm[3] - M);
    float Lc = pl[0]*e0 + pl[1]*e1 + pl[2]*e2 + pl[3]*e3;
    float cc = pctx[0][t]*e0 + pctx[1][t]*e1 + pctx[2][t]*e2 + pctx[3][t]*e3;

    float* part = ws + WS_PART + (size_t)blk * PART_STRIDE;
    part[t] = cc;
    if (t == 0) {
        float bbv = pbv[0]; int bbi = pbi[0];
        #pragma unroll
        for (int i = 1; i < 4; ++i)
            if (pbv[i] > bbv || (pbv[i] == bbv && pbi[i] < bbi)) { bbv = pbv[i]; bbi = pbi[i]; }
        part[256] = M; part[257] = Lc; part[258] = bbv; part[259] = (float)bbi;
    }
}

// ---------------- Kernel C: combine partials + projections + scatter ----------------
__global__ __launch_bounds__(256) void finalize(
    const float* __restrict__ W2, const float* __restrict__ b2,
    const float* __restrict__ W3, const float* __restrict__ b3,
    float* __restrict__ ws, float* __restrict__ out)
{
    const int b = blockIdx.x, t = threadIdx.x;
    __shared__ float marr[128], mred[128], lred[128], e_sh[128], bvred[128];
    __shared__ int bired[128];
    __shared__ __align__(16) float ctx_s[HH], cx_s[HH], hn_s[HH];

    const float* parts = ws + WS_PART + (size_t)b * CHUNKS_PER_B * PART_STRIDE;
    float lraw = 0.0f;
    if (t < 128) {
        const float* p = parts + (size_t)t * PART_STRIDE + 256;
        float mv = p[0]; lraw = p[1];
        marr[t] = mv; mred[t] = mv;
        bvred[t] = p[2]; bired[t] = (int)p[3];
    }
    __syncthreads();
    for (int s = 64; s > 0; s >>= 1) {
        if (t < s) {
            mred[t] = fmaxf(mred[t], mred[t + s]);
            if (bvred[t + s] > bvred[t] ||
                (bvred[t + s] == bvred[t] && bired[t + s] < bired[t])) {
                bvred[t] = bvred[t + s]; bired[t] = bired[t + s];
            }
        }
        __syncthreads();
    }
    const float M = mred[0];
    if (t < 128) {
        float e = __expf(marr[t] - M);
        e_sh[t] = e;
        lred[t] = lraw * e;
    }
    __syncthreads();
    for (int s = 64; s > 0; s >>= 1) {
        if (t < s) lred[t] += lred[t + s];
        __syncthreads();
    }
    const float L = lred[0];
    const int best = bired[0];

    // ctx_raw[t] = (sum_c part_c[t] * e_c) / L
    float acc = 0.0f;
    for (int c = 0; c < CHUNKS_PER_B; ++c)
        acc += parts[(size_t)c * PART_STRIDE + t] * e_sh[c];
    ctx_s[t] = acc / L;
    hn_s[t] = ws[WS_HNEW + b * HH + t];
    __syncthreads();

    // context[t] = W2[t,:] . ctx_raw + b2[t]
    float cacc = b2[t];
    {
        const float4* W24 = (const float4*)(W2 + (size_t)t * HH);
        const float4* cr4 = (const float4*)ctx_s;
        #pragma unroll 4
        for (int k = 0; k < HH/4; ++k) {
            float4 wv = W24[k], cv = cr4[k];
            cacc += wv.x*cv.x + wv.y*cv.y + wv.z*cv.z + wv.w*cv.w;
        }
    }
    cx_s[t] = cacc;
    __syncthreads();

    // result[t] = W3[t,:] . [context, h_new] + b3[t]
    float racc = b3[t];
    {
        const float4* W34 = (const float4*)(W3 + (size_t)t * 2 * HH);
        const float4* cx4 = (const float4*)cx_s;
        const float4* hn4 = (const float4*)hn_s;
        #pragma unroll 4
        for (int k = 0; k < HH/4; ++k) {
            float4 wv = W34[k], cv = cx4[k];
            racc += wv.x*cv.x + wv.y*cv.y + wv.z*cv.z + wv.w*cv.w;
        }
        #pragma unroll 4
        for (int k = 0; k < HH/4; ++k) {
            float4 wv = W34[HH/4 + k], hv = hn4[k];
            racc += wv.x*hv.x + wv.y*hv.y + wv.z*hv.z + wv.w*hv.w;
        }
    }
    out[OUT_RESULT + b * HH + t] = racc;

    if (t == 0) {
        out[OUT_EV + b] = (float)best;
        out[OUT_MASK + (size_t)b * SS + best] = NEGV;
    }
}

extern "C" void kernel_launch(void* const* d_in, const int* in_sizes, int n_in,
                              void* d_out, int out_size, void* d_ws, size_t ws_size,
                              hipStream_t stream) {
    const float* last_hidden = (const float*)d_in[0];
    const float* dec         = (const float*)d_in[1];
    const float* eo          = (const float*)d_in[2];
    const float* mask        = (const float*)d_in[3];
    const float* gum         = (const float*)d_in[4];
    const float* W1          = (const float*)d_in[5];
    const float* b1          = (const float*)d_in[6];
    const float* W2          = (const float*)d_in[7];
    const float* b2          = (const float*)d_in[8];
    const float* W3          = (const float*)d_in[9];
    const float* b3          = (const float*)d_in[10];
    const float* W_ih        = (const float*)d_in[11];
    const float* W_hh        = (const float*)d_in[12];
    const float* b_ih        = (const float*)d_in[13];
    const float* b_hh        = (const float*)d_in[14];
    float* out = (float*)d_out;
    float* ws  = (float*)d_ws;

    hipLaunchKernelGGL(gru_prep, dim3(BB), dim3(256), 0, stream,
                       last_hidden, dec, W1, b1, W_ih, W_hh, b_ih, b_hh, ws, out);
    hipLaunchKernelGGL(attn_main, dim3(BB * CHUNKS_PER_B), dim3(256), 0, stream,
                       eo, mask, gum, ws, out);
    hipLaunchKernelGGL(finalize, dim3(BB), dim3(256), 0, stream,
                       W2, b2, W3, b3, ws, out);
}

// Round 2
// 148.934 us; speedup vs baseline: 1.0065x; 1.0065x over previous
//
#include <hip/hip_runtime.h>
#include <math.h>

// Problem constants
#define HH 256
#define SS 32768
#define BB 8
#define NEGV (-10000000000.0f)

// Output layout (floats): result(2048) | h_new(2048) | evidence(8) | attn(262144) | new_mask(262144)
#define OUT_RESULT 0
#define OUT_HNEW   2048
#define OUT_EV     4096
#define OUT_ATT    4104
#define OUT_MASK   266248

// Workspace layout (floats)
#define WS_HNEW 0
#define WS_Q1   2048
#define WS_C1   4096
#define WS_PART 4112
#define PART_STRIDE 264   // ctx[256] + m,l,bestv,bestidx (+pad)
#define CHUNKS_PER_B 256  // 256 chunks * 128 s = 32768
#define S_PER_BLOCK 128
#define S_PER_WAVE 32

__device__ __forceinline__ float rl(float x, int srclane) {
    return __int_as_float(__builtin_amdgcn_readlane(__float_as_int(x), srclane));
}

// ---------------- Kernel A: GRU step + q1/c1 precompute ----------------
__global__ __launch_bounds__(256) void gru_prep(
    const float* __restrict__ last_hidden, const float* __restrict__ dec_in,
    const float* __restrict__ W1, const float* __restrict__ b1,
    const float* __restrict__ W_ih, const float* __restrict__ W_hh,
    const float* __restrict__ b_ih, const float* __restrict__ b_hh,
    float* __restrict__ ws, float* __restrict__ out)
{
    const int b = blockIdx.x, t = threadIdx.x;
    __shared__ __align__(16) float xs[HH], hs[HH], hn[HH];
    __shared__ float red[256];
    xs[t] = dec_in[b * HH + t];          // decoder_inputs (B,1,H)
    hs[t] = last_hidden[b * HH + t];     // last_hidden (1,B,H)
    __syncthreads();

    const float4* Wi4 = (const float4*)W_ih;
    const float4* Wh4 = (const float4*)W_hh;
    const float4* xs4 = (const float4*)xs;
    const float4* hs4 = (const float4*)hs;

    float gi0 = b_ih[t], gi1 = b_ih[t + HH], gi2 = b_ih[t + 2 * HH];
    float gh0 = b_hh[t], gh1 = b_hh[t + HH], gh2 = b_hh[t + 2 * HH];
    #pragma unroll 4
    for (int k4 = 0; k4 < HH / 4; ++k4) {
        float4 xv = xs4[k4], hv = hs4[k4];
        float4 a0 = Wi4[(size_t)(t)          * (HH/4) + k4];
        float4 a1 = Wi4[(size_t)(t + HH)     * (HH/4) + k4];
        float4 a2 = Wi4[(size_t)(t + 2*HH)   * (HH/4) + k4];
        float4 c0 = Wh4[(size_t)(t)          * (HH/4) + k4];
        float4 c1v= Wh4[(size_t)(t + HH)     * (HH/4) + k4];
        float4 c2 = Wh4[(size_t)(t + 2*HH)   * (HH/4) + k4];
        gi0 += xv.x*a0.x + xv.y*a0.y + xv.z*a0.z + xv.w*a0.w;
        gi1 += xv.x*a1.x + xv.y*a1.y + xv.z*a1.z + xv.w*a1.w;
        gi2 += xv.x*a2.x + xv.y*a2.y + xv.z*a2.z + xv.w*a2.w;
        gh0 += hv.x*c0.x + hv.y*c0.y + hv.z*c0.z + hv.w*c0.w;
        gh1 += hv.x*c1v.x+ hv.y*c1v.y+ hv.z*c1v.z+ hv.w*c1v.w;
        gh2 += hv.x*c2.x + hv.y*c2.y + hv.z*c2.z + hv.w*c2.w;
    }
    float r = 1.0f / (1.0f + expf(-(gi0 + gh0)));
    float z = 1.0f / (1.0f + expf(-(gi1 + gh1)));
    float n = tanhf(gi2 + r * gh2);
    float hnew = (1.0f - z) * n + z * hs[t];

    ws[WS_HNEW + b * HH + t] = hnew;
    out[OUT_HNEW + b * HH + t] = hnew;
    hn[t] = hnew;
    red[t] = hnew * b1[t];
    __syncthreads();

    // q1[k] = sum_h hn[h] * W1[h,k]  (coalesced over t=k)
    float acc = 0.0f;
    #pragma unroll 4
    for (int h = 0; h < HH; ++h) acc += hn[h] * W1[(size_t)h * HH + t];
    ws[WS_Q1 + b * HH + t] = acc;

    // c1 = hn . b1
    for (int s = 128; s > 0; s >>= 1) {
        if (t < s) red[t] += red[t + s];
        __syncthreads();
    }
    if (t == 0) ws[WS_C1 + b] = red[0];
}

// ---------------- Kernel B: streaming scores + online softmax context ----------------
__global__ __launch_bounds__(256, 4) void attn_main(
    const float* __restrict__ eo, const float* __restrict__ mask,
    const float* __restrict__ gum, float* __restrict__ ws,
    float* __restrict__ out)
{
    const int blk = blockIdx.x;
    const int b = blk >> 8;            // CHUNKS_PER_B = 256
    const int chunk = blk & 255;
    const int t = threadIdx.x;
    const int w = t >> 6, lane = t & 63;
    const int sbase = chunk * S_PER_BLOCK;
    const int swave = sbase + w * S_PER_WAVE;

    // mask pass-through copy (evidence slot overwritten by finalize)
    if (t < S_PER_BLOCK)
        out[OUT_MASK + (size_t)b * SS + sbase + t] = mask[(size_t)b * SS + sbase + t];

    const float4 q = ((const float4*)(ws + WS_Q1 + b * HH))[lane];
    const float c1 = ws[WS_C1 + b];

    float mk = 0.0f, gl = 0.0f;
    if (lane < S_PER_WAVE) {
        mk = mask[(size_t)b * SS + swave + lane];
        float uu = gum[(size_t)b * SS + swave + lane];
        gl = -logf(-logf(uu));
    }

    const float4* base = (const float4*)(eo + ((size_t)b * SS + swave) * HH);

    float m = -INFINITY, l = 0.0f;
    float bv = -INFINITY; int bi = 0;
    float4 ctx = {0.f, 0.f, 0.f, 0.f};
    float my_t = 0.0f;

    // prefetch group 0 (4 rows = 4KB/wave)
    float4 a0 = base[0 * 64 + lane];
    float4 a1 = base[1 * 64 + lane];
    float4 a2 = base[2 * 64 + lane];
    float4 a3 = base[3 * 64 + lane];

    #pragma unroll
    for (int g = 0; g < S_PER_WAVE / 4; ++g) {
        float4 n0, n1, n2, n3;
        if (g < S_PER_WAVE / 4 - 1) {
            const float4* nb = base + (size_t)(g + 1) * 4 * 64;
            n0 = nb[0 * 64 + lane];
            n1 = nb[1 * 64 + lane];
            n2 = nb[2 * 64 + lane];
            n3 = nb[3 * 64 + lane];
        }

        // per-lane partial dots for 4 rows
        float p0 = a0.x*q.x + a0.y*q.y + a0.z*q.z + a0.w*q.w;
        float p1 = a1.x*q.x + a1.y*q.y + a1.z*q.z + a1.w*q.w;
        float p2 = a2.x*q.x + a2.y*q.y + a2.z*q.z + a2.w*q.w;
        float p3 = a3.x*q.x + a3.y*q.y + a3.z*q.z + a3.w*q.w;

        // merged 4-way reduction: 7 shuffles total, result for row i in lane%4==i
        const bool lb0 = lane & 1;
        float r01 = (lb0 ? p1 : p0) + __shfl_xor(lb0 ? p0 : p1, 1);
        float r23 = (lb0 ? p3 : p2) + __shfl_xor(lb0 ? p2 : p3, 1);
        const bool lb1 = lane & 2;
        float r = (lb1 ? r23 : r01) + __shfl_xor(lb1 ? r01 : r23, 2);
        r += __shfl_xor(r, 4);
        r += __shfl_xor(r, 8);
        r += __shfl_xor(r, 16);
        r += __shfl_xor(r, 32);

        float tg0, tg1, tg2, tg3;
        #pragma unroll
        for (int i = 0; i < 4; ++i) {
            float d  = rl(r, i);                 // full dot for row i (uniform)
            float tt = d + c1 + rl(mk, 4 * g + i);
            if (lane == 4 * g + i) my_t = tt;
            float tgi = tt + rl(gl, 4 * g + i);
            if (tgi > bv) { bv = tgi; bi = swave + 4 * g + i; }  // first-max tie-break
            if (i == 0) tg0 = tgi; else if (i == 1) tg1 = tgi;
            else if (i == 2) tg2 = tgi; else tg3 = tgi;
        }

        float gmax = fmaxf(fmaxf(tg0, tg1), fmaxf(tg2, tg3));
        if (gmax > m) {                           // wave-uniform
            float sc = __expf(m - gmax);
            l *= sc; ctx.x *= sc; ctx.y *= sc; ctx.z *= sc; ctx.w *= sc;
            m = gmax;
        }
        float w0 = __expf(tg0 - m), w1 = __expf(tg1 - m);
        float w2 = __expf(tg2 - m), w3 = __expf(tg3 - m);
        l += (w0 + w1) + (w2 + w3);
        ctx.x += w0*a0.x + w1*a1.x + w2*a2.x + w3*a3.x;
        ctx.y += w0*a0.y + w1*a1.y + w2*a2.y + w3*a3.y;
        ctx.z += w0*a0.z + w1*a1.z + w2*a2.z + w3*a3.z;
        ctx.w += w0*a0.w + w1*a1.w + w2*a2.w + w3*a3.w;

        a0 = n0; a1 = n1; a2 = n2; a3 = n3;
    }

    if (lane < S_PER_WAVE)
        out[OUT_ATT + (size_t)b * SS + swave + lane] = my_t;

    // combine 4 waves -> 1 block partial
    __shared__ float pm[4], pl[4], pbv[4];
    __shared__ int pbi[4];
    __shared__ __align__(16) float pctx[4][HH];
    ((float4*)pctx[w])[lane] = ctx;
    if (lane == 0) { pm[w] = m; pl[w] = l; pbv[w] = bv; pbi[w] = bi; }
    __syncthreads();

    float M = fmaxf(fmaxf(pm[0], pm[1]), fmaxf(pm[2], pm[3]));
    float e0 = __expf(pm[0] - M), e1 = __expf(pm[1] - M);
    float e2 = __expf(pm[2] - M), e3 = __expf(pm[3] - M);
    float Lc = pl[0]*e0 + pl[1]*e1 + pl[2]*e2 + pl[3]*e3;
    float cc = pctx[0][t]*e0 + pctx[1][t]*e1 + pctx[2][t]*e2 + pctx[3][t]*e3;

    float* part = ws + WS_PART + (size_t)blk * PART_STRIDE;
    part[t] = cc;
    if (t == 0) {
        float bbv = pbv[0]; int bbi = pbi[0];
        #pragma unroll
        for (int i = 1; i < 4; ++i)
            if (pbv[i] > bbv || (pbv[i] == bbv && pbi[i] < bbi)) { bbv = pbv[i]; bbi = pbi[i]; }
        part[256] = M; part[257] = Lc; part[258] = bbv; part[259] = (float)bbi;
    }
}

// ---------------- Kernel C: combine partials + projections + scatter ----------------
__global__ __launch_bounds__(256) void finalize(
    const float* __restrict__ W2, const float* __restrict__ b2,
    const float* __restrict__ W3, const float* __restrict__ b3,
    float* __restrict__ ws, float* __restrict__ out)
{
    const int b = blockIdx.x, t = threadIdx.x;
    __shared__ float marr[256], mred[256], lred[256], e_sh[256], bvred[256];
    __shared__ int bired[256];
    __shared__ __align__(16) float ctx_s[HH], cx_s[HH], hn_s[HH];

    const float* parts = ws + WS_PART + (size_t)b * CHUNKS_PER_B * PART_STRIDE;
    const float* p = parts + (size_t)t * PART_STRIDE + 256;
    float mv = p[0], lraw = p[1];
    marr[t] = mv; mred[t] = mv;
    bvred[t] = p[2]; bired[t] = (int)p[3];
    __syncthreads();
    for (int s = 128; s > 0; s >>= 1) {
        if (t < s) {
            mred[t] = fmaxf(mred[t], mred[t + s]);
            if (bvred[t + s] > bvred[t] ||
                (bvred[t + s] == bvred[t] && bired[t + s] < bired[t])) {
                bvred[t] = bvred[t + s]; bired[t] = bired[t + s];
            }
        }
        __syncthreads();
    }
    const float M = mred[0];
    {
        float e = __expf(marr[t] - M);
        e_sh[t] = e;
        lred[t] = lraw * e;
    }
    __syncthreads();
    for (int s = 128; s > 0; s >>= 1) {
        if (t < s) lred[t] += lred[t + s];
        __syncthreads();
    }
    const float L = lred[0];
    const int best = bired[0];

    // ctx_raw[t] = (sum_c part_c[t] * e_c) / L
    float acc = 0.0f;
    for (int c = 0; c < CHUNKS_PER_B; ++c)
        acc += parts[(size_t)c * PART_STRIDE + t] * e_sh[c];
    ctx_s[t] = acc / L;
    hn_s[t] = ws[WS_HNEW + b * HH + t];
    __syncthreads();

    // context[t] = W2[t,:] . ctx_raw + b2[t]
    float cacc = b2[t];
    {
        const float4* W24 = (const float4*)(W2 + (size_t)t * HH);
        const float4* cr4 = (const float4*)ctx_s;
        #pragma unroll 4
        for (int k = 0; k < HH/4; ++k) {
            float4 wv = W24[k], cv = cr4[k];
            cacc += wv.x*cv.x + wv.y*cv.y + wv.z*cv.z + wv.w*cv.w;
        }
    }
    cx_s[t] = cacc;
    __syncthreads();

    // result[t] = W3[t,:] . [context, h_new] + b3[t]
    float racc = b3[t];
    {
        const float4* W34 = (const float4*)(W3 + (size_t)t * 2 * HH);
        const float4* cx4 = (const float4*)cx_s;
        const float4* hn4 = (const float4*)hn_s;
        #pragma unroll 4
        for (int k = 0; k < HH/4; ++k) {
            float4 wv = W34[k], cv = cx4[k];
            racc += wv.x*cv.x + wv.y*cv.y + wv.z*cv.z + wv.w*cv.w;
        }
        #pragma unroll 4
        for (int k = 0; k < HH/4; ++k) {
            float4 wv = W34[HH/4 + k], hv = hn4[k];
            racc += wv.x*hv.x + wv.y*hv.y + wv.z*hv.z + wv.w*hv.w;
        }
    }
    out[OUT_RESULT + b * HH + t] = racc;

    if (t == 0) {
        out[OUT_EV + b] = (float)best;
        out[OUT_MASK + (size_t)b * SS + best] = NEGV;
    }
}

extern "C" void kernel_launch(void* const* d_in, const int* in_sizes, int n_in,
                              void* d_out, int out_size, void* d_ws, size_t ws_size,
                              hipStream_t stream) {
    const float* last_hidden = (const float*)d_in[0];
    const float* dec         = (const float*)d_in[1];
    const float* eo          = (const float*)d_in[2];
    const float* mask        = (const float*)d_in[3];
    const float* gum         = (const float*)d_in[4];
    const float* W1          = (const float*)d_in[5];
    const float* b1          = (const float*)d_in[6];
    const float* W2          = (const float*)d_in[7];
    const float* b2          = (const float*)d_in[8];
    const float* W3          = (const float*)d_in[9];
    const float* b3          = (const float*)d_in[10];
    const float* W_ih        = (const float*)d_in[11];
    const float* W_hh        = (const float*)d_in[12];
    const float* b_ih        = (const float*)d_in[13];
    const float* b_hh        = (const float*)d_in[14];
    float* out = (float*)d_out;
    float* ws  = (float*)d_ws;

    hipLaunchKernelGGL(gru_prep, dim3(BB), dim3(256), 0, stream,
                       last_hidden, dec, W1, b1, W_ih, W_hh, b_ih, b_hh, ws, out);
    hipLaunchKernelGGL(attn_main, dim3(BB * CHUNKS_PER_B), dim3(256), 0, stream,
                       eo, mask, gum, ws, out);
    hipLaunchKernelGGL(finalize, dim3(BB), dim3(256), 0, stream,
                       W2, b2, W3, b3, ws, out);
}

// Round 3
// 91.822 us; speedup vs baseline: 1.6325x; 1.6220x over previous
//
#include <hip/hip_runtime.h>
#include <math.h>

// Problem constants
#define HH 256
#define SS 32768
#define BB 8
#define NEGV (-10000000000.0f)

// Output layout (floats): result(2048) | h_new(2048) | evidence(8) | attn(262144) | new_mask(262144)
#define OUT_RESULT 0
#define OUT_HNEW   2048
#define OUT_EV     4096
#define OUT_ATT    4104
#define OUT_MASK   266248

// Workspace layout (floats)
#define WS_HNEW  0
#define WS_Q1    2048
#define WS_C1    4096
#define WS_GATES 4112              // 1536 rows x 8 batches (transposed gates)
#define WS_PART  (4112 + 12288)    // 16400
#define PART_STRIDE 264            // ctx[256] + m,l,bestv,bestidx (+pad)
#define CHUNKS_PER_B 256           // 256 chunks * 128 s = 32768
#define S_PER_BLOCK 128
#define S_PER_WAVE 32

__device__ __forceinline__ float rl(float x, int srclane) {
    return __int_as_float(__builtin_amdgcn_readlane(__float_as_int(x), srclane));
}

// ---------------- Kernel A1: row-parallel gates GEMV ----------------
// gatesT[r*8+b] = dot(W_ih[r,:], x[b,:])      for r in [0,768)
// gatesT[(768+j)*8+b] = dot(W_hh[j,:], h[b,:]) for j in [0,768)
__global__ __launch_bounds__(256) void gates_gemv(
    const float* __restrict__ dec_in, const float* __restrict__ last_hidden,
    const float* __restrict__ W_ih, const float* __restrict__ W_hh,
    float* __restrict__ ws)
{
    const int t = threadIdx.x;
    const int w = t >> 6, lane = t & 63;
    __shared__ __align__(16) float4 xs4[BB][HH / 4];
    __shared__ __align__(16) float4 hs4[BB][HH / 4];
    {
        float* xf = (float*)xs4;
        float* hf = (float*)hs4;
        #pragma unroll
        for (int i = 0; i < 8; ++i) {
            int idx = i * 256 + t;          // 2048 floats
            xf[idx] = dec_in[idx];          // (B,1,H) flat
            hf[idx] = last_hidden[idx];     // (1,B,H) flat
        }
    }
    __syncthreads();

    const int rbase = blockIdx.x * 16 + w * 4;   // 96 blocks * 16 rows
    #pragma unroll
    for (int rr = 0; rr < 4; ++rr) {
        const int r = rbase + rr;
        const bool ih = (r < 768);
        const float* Wrow = ih ? (W_ih + (size_t)r * HH) : (W_hh + (size_t)(r - 768) * HH);
        const float4 rv = ((const float4*)Wrow)[lane];
        const float4 (*src)[HH / 4] = ih ? xs4 : hs4;

        float p[8];
        #pragma unroll
        for (int b = 0; b < 8; ++b) {
            float4 xv = src[b][lane];
            p[b] = rv.x * xv.x + rv.y * xv.y + rv.z * xv.z + rv.w * xv.w;
        }
        // merged 8-way butterfly: 10 shuffles; lane&7==b holds full dot for batch b
        const bool l1 = lane & 1;
        float q01 = (l1 ? p[1] : p[0]) + __shfl_xor(l1 ? p[0] : p[1], 1);
        float q23 = (l1 ? p[3] : p[2]) + __shfl_xor(l1 ? p[2] : p[3], 1);
        float q45 = (l1 ? p[5] : p[4]) + __shfl_xor(l1 ? p[4] : p[5], 1);
        float q67 = (l1 ? p[7] : p[6]) + __shfl_xor(l1 ? p[6] : p[7], 1);
        const bool l2 = lane & 2;
        float r03 = (l2 ? q23 : q01) + __shfl_xor(l2 ? q01 : q23, 2);
        float r47 = (l2 ? q67 : q45) + __shfl_xor(l2 ? q45 : q67, 2);
        const bool l4 = lane & 4;
        float s = (l4 ? r47 : r03) + __shfl_xor(l4 ? r03 : r47, 4);
        s += __shfl_xor(s, 8);
        s += __shfl_xor(s, 16);
        s += __shfl_xor(s, 32);

        if (lane < 8)
            ws[WS_GATES + (size_t)r * 8 + lane] = s;
    }
}

// ---------------- Kernel A2: GRU combine + q1/c1 ----------------
__global__ __launch_bounds__(256) void gru_combine(
    const float* __restrict__ last_hidden,
    const float* __restrict__ W1, const float* __restrict__ b1,
    const float* __restrict__ b_ih, const float* __restrict__ b_hh,
    float* __restrict__ ws, float* __restrict__ out)
{
    const int b = blockIdx.x, t = threadIdx.x;
    __shared__ float hn[HH];
    __shared__ float red[256];

    const float* gT = ws + WS_GATES;
    float gi0 = gT[(size_t)(t)         * 8 + b] + b_ih[t];
    float gi1 = gT[(size_t)(t + HH)    * 8 + b] + b_ih[t + HH];
    float gi2 = gT[(size_t)(t + 2*HH)  * 8 + b] + b_ih[t + 2*HH];
    float gh0 = gT[(size_t)(768 + t)        * 8 + b] + b_hh[t];
    float gh1 = gT[(size_t)(768 + t + HH)   * 8 + b] + b_hh[t + HH];
    float gh2 = gT[(size_t)(768 + t + 2*HH) * 8 + b] + b_hh[t + 2*HH];

    const float hprev = last_hidden[b * HH + t];
    float r = 1.0f / (1.0f + expf(-(gi0 + gh0)));
    float z = 1.0f / (1.0f + expf(-(gi1 + gh1)));
    float n = tanhf(gi2 + r * gh2);
    float hnew = (1.0f - z) * n + z * hprev;

    ws[WS_HNEW + b * HH + t] = hnew;
    out[OUT_HNEW + b * HH + t] = hnew;
    hn[t] = hnew;
    red[t] = hnew * b1[t];
    __syncthreads();

    // q1[k] = sum_h hn[h] * W1[h,k]  — coalesced column sweep, 4 accumulators
    float a0 = 0.f, a1 = 0.f, a2 = 0.f, a3 = 0.f;
    #pragma unroll 8
    for (int h = 0; h < HH; h += 4) {
        a0 += hn[h]     * W1[(size_t)(h)     * HH + t];
        a1 += hn[h + 1] * W1[(size_t)(h + 1) * HH + t];
        a2 += hn[h + 2] * W1[(size_t)(h + 2) * HH + t];
        a3 += hn[h + 3] * W1[(size_t)(h + 3) * HH + t];
    }
    ws[WS_Q1 + b * HH + t] = (a0 + a1) + (a2 + a3);

    // c1 = hn . b1
    for (int s = 128; s > 0; s >>= 1) {
        if (t < s) red[t] += red[t + s];
        __syncthreads();
    }
    if (t == 0) ws[WS_C1 + b] = red[0];
}

// ---------------- Kernel B: streaming scores + online softmax context ----------------
__global__ __launch_bounds__(256, 4) void attn_main(
    const float* __restrict__ eo, const float* __restrict__ mask,
    const float* __restrict__ gum, float* __restrict__ ws,
    float* __restrict__ out)
{
    const int blk = blockIdx.x;
    const int b = blk >> 8;            // CHUNKS_PER_B = 256
    const int chunk = blk & 255;
    const int t = threadIdx.x;
    const int w = t >> 6, lane = t & 63;
    const int sbase = chunk * S_PER_BLOCK;
    const int swave = sbase + w * S_PER_WAVE;

    // mask pass-through copy (evidence slot overwritten by finalize)
    if (t < S_PER_BLOCK)
        out[OUT_MASK + (size_t)b * SS + sbase + t] = mask[(size_t)b * SS + sbase + t];

    const float4 q = ((const float4*)(ws + WS_Q1 + b * HH))[lane];
    const float c1 = ws[WS_C1 + b];

    float mk = 0.0f, gl = 0.0f;
    if (lane < S_PER_WAVE) {
        mk = mask[(size_t)b * SS + swave + lane];
        float uu = gum[(size_t)b * SS + swave + lane];
        gl = -logf(-logf(uu));
    }

    const float4* base = (const float4*)(eo + ((size_t)b * SS + swave) * HH);

    float m = -INFINITY, l = 0.0f;
    float bv = -INFINITY; int bi = 0;
    float4 ctx = {0.f, 0.f, 0.f, 0.f};
    float my_t = 0.0f;

    // prefetch group 0 (4 rows = 4KB/wave)
    float4 a0 = base[0 * 64 + lane];
    float4 a1 = base[1 * 64 + lane];
    float4 a2 = base[2 * 64 + lane];
    float4 a3 = base[3 * 64 + lane];

    #pragma unroll
    for (int g = 0; g < S_PER_WAVE / 4; ++g) {
        float4 n0, n1, n2, n3;
        if (g < S_PER_WAVE / 4 - 1) {
            const float4* nb = base + (size_t)(g + 1) * 4 * 64;
            n0 = nb[0 * 64 + lane];
            n1 = nb[1 * 64 + lane];
            n2 = nb[2 * 64 + lane];
            n3 = nb[3 * 64 + lane];
        }

        // per-lane partial dots for 4 rows
        float p0 = a0.x*q.x + a0.y*q.y + a0.z*q.z + a0.w*q.w;
        float p1 = a1.x*q.x + a1.y*q.y + a1.z*q.z + a1.w*q.w;
        float p2 = a2.x*q.x + a2.y*q.y + a2.z*q.z + a2.w*q.w;
        float p3 = a3.x*q.x + a3.y*q.y + a3.z*q.z + a3.w*q.w;

        // merged 4-way reduction: 7 shuffles total, result for row i in lane%4==i
        const bool lb0 = lane & 1;
        float r01 = (lb0 ? p1 : p0) + __shfl_xor(lb0 ? p0 : p1, 1);
        float r23 = (lb0 ? p3 : p2) + __shfl_xor(lb0 ? p2 : p3, 1);
        const bool lb1 = lane & 2;
        float r = (lb1 ? r23 : r01) + __shfl_xor(lb1 ? r01 : r23, 2);
        r += __shfl_xor(r, 4);
        r += __shfl_xor(r, 8);
        r += __shfl_xor(r, 16);
        r += __shfl_xor(r, 32);

        float tg0, tg1, tg2, tg3;
        #pragma unroll
        for (int i = 0; i < 4; ++i) {
            float d  = rl(r, i);                 // full dot for row i (uniform)
            float tt = d + c1 + rl(mk, 4 * g + i);
            if (lane == 4 * g + i) my_t = tt;
            float tgi = tt + rl(gl, 4 * g + i);
            if (tgi > bv) { bv = tgi; bi = swave + 4 * g + i; }  // first-max tie-break
            if (i == 0) tg0 = tgi; else if (i == 1) tg1 = tgi;
            else if (i == 2) tg2 = tgi; else tg3 = tgi;
        }

        float gmax = fmaxf(fmaxf(tg0, tg1), fmaxf(tg2, tg3));
        if (gmax > m) {                           // wave-uniform
            float sc = __expf(m - gmax);
            l *= sc; ctx.x *= sc; ctx.y *= sc; ctx.z *= sc; ctx.w *= sc;
            m = gmax;
        }
        float w0 = __expf(tg0 - m), w1 = __expf(tg1 - m);
        float w2 = __expf(tg2 - m), w3 = __expf(tg3 - m);
        l += (w0 + w1) + (w2 + w3);
        ctx.x += w0*a0.x + w1*a1.x + w2*a2.x + w3*a3.x;
        ctx.y += w0*a0.y + w1*a1.y + w2*a2.y + w3*a3.y;
        ctx.z += w0*a0.z + w1*a1.z + w2*a2.z + w3*a3.z;
        ctx.w += w0*a0.w + w1*a1.w + w2*a2.w + w3*a3.w;

        a0 = n0; a1 = n1; a2 = n2; a3 = n3;
    }

    if (lane < S_PER_WAVE)
        out[OUT_ATT + (size_t)b * SS + swave + lane] = my_t;

    // combine 4 waves -> 1 block partial
    __shared__ float pm[4], pl[4], pbv[4];
    __shared__ int pbi[4];
    __shared__ __align__(16) float pctx[4][HH];
    ((float4*)pctx[w])[lane] = ctx;
    if (lane == 0) { pm[w] = m; pl[w] = l; pbv[w] = bv; pbi[w] = bi; }
    __syncthreads();

    float M = fmaxf(fmaxf(pm[0], pm[1]), fmaxf(pm[2], pm[3]));
    float e0 = __expf(pm[0] - M), e1 = __expf(pm[1] - M);
    float e2 = __expf(pm[2] - M), e3 = __expf(pm[3] - M);
    float Lc = pl[0]*e0 + pl[1]*e1 + pl[2]*e2 + pl[3]*e3;
    float cc = pctx[0][t]*e0 + pctx[1][t]*e1 + pctx[2][t]*e2 + pctx[3][t]*e3;

    float* part = ws + WS_PART + (size_t)blk * PART_STRIDE;
    part[t] = cc;
    if (t == 0) {
        float bbv = pbv[0]; int bbi = pbi[0];
        #pragma unroll
        for (int i = 1; i < 4; ++i)
            if (pbv[i] > bbv || (pbv[i] == bbv && pbi[i] < bbi)) { bbv = pbv[i]; bbi = pbi[i]; }
        part[256] = M; part[257] = Lc; part[258] = bbv; part[259] = (float)bbi;
    }
}

// ---------------- Kernel C: combine partials + projections + scatter ----------------
__global__ __launch_bounds__(256) void finalize(
    const float* __restrict__ W2, const float* __restrict__ b2,
    const float* __restrict__ W3, const float* __restrict__ b3,
    float* __restrict__ ws, float* __restrict__ out)
{
    const int b = blockIdx.x, t = threadIdx.x;
    __shared__ float marr[256], mred[256], lred[256], e_sh[256], bvred[256];
    __shared__ int bired[256];
    __shared__ __align__(16) float ctx_s[HH], cx_s[HH], hn_s[HH];

    const float* parts = ws + WS_PART + (size_t)b * CHUNKS_PER_B * PART_STRIDE;
    const float* p = parts + (size_t)t * PART_STRIDE + 256;
    float mv = p[0], lraw = p[1];
    marr[t] = mv; mred[t] = mv;
    bvred[t] = p[2]; bired[t] = (int)p[3];
    __syncthreads();
    for (int s = 128; s > 0; s >>= 1) {
        if (t < s) {
            mred[t] = fmaxf(mred[t], mred[t + s]);
            if (bvred[t + s] > bvred[t] ||
                (bvred[t + s] == bvred[t] && bired[t + s] < bired[t])) {
                bvred[t] = bvred[t + s]; bired[t] = bired[t + s];
            }
        }
        __syncthreads();
    }
    const float M = mred[0];
    {
        float e = __expf(marr[t] - M);
        e_sh[t] = e;
        lred[t] = lraw * e;
    }
    __syncthreads();
    for (int s = 128; s > 0; s >>= 1) {
        if (t < s) lred[t] += lred[t + s];
        __syncthreads();
    }
    const float L = lred[0];
    const int best = bired[0];

    // ctx_raw[t] = (sum_c part_c[t] * e_c) / L
    float acc = 0.0f;
    for (int c = 0; c < CHUNKS_PER_B; ++c)
        acc += parts[(size_t)c * PART_STRIDE + t] * e_sh[c];
    ctx_s[t] = acc / L;
    hn_s[t] = ws[WS_HNEW + b * HH + t];
    __syncthreads();

    // context[t] = W2[t,:] . ctx_raw + b2[t]
    float cacc = b2[t];
    {
        const float4* W24 = (const float4*)(W2 + (size_t)t * HH);
        const float4* cr4 = (const float4*)ctx_s;
        #pragma unroll 4
        for (int k = 0; k < HH/4; ++k) {
            float4 wv = W24[k], cv = cr4[k];
            cacc += wv.x*cv.x + wv.y*cv.y + wv.z*cv.z + wv.w*cv.w;
        }
    }
    cx_s[t] = cacc;
    __syncthreads();

    // result[t] = W3[t,:] . [context, h_new] + b3[t]
    float racc = b3[t];
    {
        const float4* W34 = (const float4*)(W3 + (size_t)t * 2 * HH);
        const float4* cx4 = (const float4*)cx_s;
        const float4* hn4 = (const float4*)hn_s;
        #pragma unroll 4
        for (int k = 0; k < HH/4; ++k) {
            float4 wv = W34[k], cv = cx4[k];
            racc += wv.x*cv.x + wv.y*cv.y + wv.z*cv.z + wv.w*cv.w;
        }
        #pragma unroll 4
        for (int k = 0; k < HH/4; ++k) {
            float4 wv = W34[HH/4 + k], hv = hn4[k];
            racc += wv.x*hv.x + wv.y*hv.y + wv.z*hv.z + wv.w*hv.w;
        }
    }
    out[OUT_RESULT + b * HH + t] = racc;

    if (t == 0) {
        out[OUT_EV + b] = (float)best;
        out[OUT_MASK + (size_t)b * SS + best] = NEGV;
    }
}

extern "C" void kernel_launch(void* const* d_in, const int* in_sizes, int n_in,
                              void* d_out, int out_size, void* d_ws, size_t ws_size,
                              hipStream_t stream) {
    const float* last_hidden = (const float*)d_in[0];
    const float* dec         = (const float*)d_in[1];
    const float* eo          = (const float*)d_in[2];
    const float* mask        = (const float*)d_in[3];
    const float* gum         = (const float*)d_in[4];
    const float* W1          = (const float*)d_in[5];
    const float* b1          = (const float*)d_in[6];
    const float* W2          = (const float*)d_in[7];
    const float* b2          = (const float*)d_in[8];
    const float* W3          = (const float*)d_in[9];
    const float* b3          = (const float*)d_in[10];
    const float* W_ih        = (const float*)d_in[11];
    const float* W_hh        = (const float*)d_in[12];
    const float* b_ih        = (const float*)d_in[13];
    const float* b_hh        = (const float*)d_in[14];
    float* out = (float*)d_out;
    float* ws  = (float*)d_ws;

    hipLaunchKernelGGL(gates_gemv, dim3(96), dim3(256), 0, stream,
                       dec, last_hidden, W_ih, W_hh, ws);
    hipLaunchKernelGGL(gru_combine, dim3(BB), dim3(256), 0, stream,
                       last_hidden, W1, b1, b_ih, b_hh, ws, out);
    hipLaunchKernelGGL(attn_main, dim3(BB * CHUNKS_PER_B), dim3(256), 0, stream,
                       eo, mask, gum, ws, out);
    hipLaunchKernelGGL(finalize, dim3(BB), dim3(256), 0, stream,
                       W2, b2, W3, b3, ws, out);
}